// Round 5
// baseline (357.771 us; speedup 1.0000x reference)
//
#include <hip/hip_runtime.h>
#include <cstdint>

typedef __bf16 bf16;
typedef __bf16 bf16x8 __attribute__((ext_vector_type(8)));
typedef __bf16 bf16x4 __attribute__((ext_vector_type(4)));
typedef float  f32x4  __attribute__((ext_vector_type(4)));

#define MFMA16(a,b,c) __builtin_amdgcn_mfma_f32_16x16x32_bf16((a),(b),(c),0,0,0)
#define SCALE2 0.18033688011f   /* 0.125 * log2(e), folded into Q projection */

__device__ __forceinline__ void gload_lds16(const void* g, void* lds) {
  __builtin_amdgcn_global_load_lds((const __attribute__((address_space(1))) uint32_t*)g,
                                   (__attribute__((address_space(3))) uint32_t*)lds, 16, 0, 0);
}

// Stage a [rows=R] x [BK=PANELS*32] bf16 tile from global (row-major, leading dim ld)
// into LDS as PANELS x [R][32] panels, linear order, via global_load_lds width=16.
template<int R, int PANELS>
__device__ __forceinline__ void stage_tile(const bf16* __restrict__ g, int r0, int k0,
                                           int ld, char* lds) {
  const int t = threadIdx.x;
  constexpr int NISSUE = (PANELS * R * 64) / 4096;   // bytes/4096 (256 thr * 16B)
#pragma unroll
  for (int i = 0; i < NISSUE; ++i) {
    int idx = i * 256 + t;
    int c = idx & 3;                 // 16B chunk within 32-elem panel row
    int r = (idx >> 2) & (R - 1);    // row
    int p = idx / (4 * R);           // panel
    const bf16* gp = g + (size_t)(r0 + r) * ld + (k0 + p * 32 + c * 8);
    char* lp = lds + i * 4096 + (t & 192) * 16;      // wave-uniform base; HW adds lane*16
    gload_lds16(gp, lp);
  }
}

// Read an MFMA fragment (8 bf16, k-contiguous) from a panel-32 LDS tile.
__device__ __forceinline__ bf16x8 ldsfrag(const char* lds, int R, int rowBase, int panel) {
  const int lane = threadIdx.x & 63;
  int off = ((panel * R + rowBase + (lane & 15)) * 32 + (lane >> 4) * 8) * 2;
  return *(const bf16x8*)(lds + off);
}

// ---------------- convert fp32 -> bf16 (inputs + weights) ----------------
__global__ void k_cvt(const float* __restrict__ qin, const float* __restrict__ kin,
                      const float* __restrict__ vin,
                      const float* __restrict__ wq, const float* __restrict__ wk,
                      const float* __restrict__ wv, const float* __restrict__ wo,
                      bf16* __restrict__ oq, bf16* __restrict__ ok, bf16* __restrict__ ov,
                      bf16* __restrict__ wqkv, bf16* __restrict__ owo) {
  long i = (long)blockIdx.x * 256 + threadIdx.x;   // chunk of 8 elems; 2097152 total
  const float* s; bf16* d; long off;
  if (i < 524288)       { s = qin; d = oq; off = i; }
  else if (i < 1048576) { s = kin; d = ok; off = i - 524288; }
  else if (i < 1572864) { s = vin; d = ov; off = i - 1048576; }
  else {
    long j = i - 1572864; int sel = (int)(j >> 17); off = j & 131071;
    s = sel == 0 ? wq : sel == 1 ? wk : sel == 2 ? wv : wo;
    d = sel == 3 ? owo : wqkv + (size_t)sel * 1048576;
  }
  const float4* sp = (const float4*)s + off * 2;
  float4 a = sp[0], b = sp[1];
  bf16x8 o;
  o[0] = (bf16)a.x; o[1] = (bf16)a.y; o[2] = (bf16)a.z; o[3] = (bf16)a.w;
  o[4] = (bf16)b.x; o[5] = (bf16)b.y; o[6] = (bf16)b.z; o[7] = (bf16)b.w;
  *((bf16x8*)d + off) = o;
}

// ---------------- pack mask & key_padding_mask into bit-words ----------------
__global__ void k_maskpack(const int* __restrict__ mask, const int* __restrict__ kpm,
                           unsigned long long* __restrict__ vm) {
  int i = blockIdx.x * 256 + threadIdx.x;          // [b][q][w] word; 131072 total
  int w = i & 31, q = (i >> 5) & 2047, b = i >> 16;
  const int4* mrow = (const int4*)(mask + (size_t)q * 2048 + w * 64);
  const int4* krow = (const int4*)(kpm + (size_t)b * 2048 + w * 64);
  unsigned long long bits = 0;
#pragma unroll
  for (int j = 0; j < 16; ++j) {
    int4 m4 = mrow[j], k4 = krow[j];
    bits |= (unsigned long long)((m4.x != 0) & (k4.x != 0)) << (j * 4 + 0);
    bits |= (unsigned long long)((m4.y != 0) & (k4.y != 0)) << (j * 4 + 1);
    bits |= (unsigned long long)((m4.z != 0) & (k4.z != 0)) << (j * 4 + 2);
    bits |= (unsigned long long)((m4.w != 0) & (k4.w != 0)) << (j * 4 + 3);
  }
  vm[i] = bits;
}

// ---------------- combined QKV projection: C = X @ Wqkv[n0:n0+128]^T ----------------
// mode 0 (Q) epilogue pre-folds SCALE2 so the attention exp chain needs no multiply.
__launch_bounds__(256, 2)
__global__ void k_proj(const bf16* __restrict__ xq, const bf16* __restrict__ xk,
                       const bf16* __restrict__ xv, const bf16* __restrict__ Wqkv,
                       bf16* __restrict__ Qo, bf16* __restrict__ Ko,
                       bf16* __restrict__ Vt) {
  __shared__ __align__(16) char Alds[8192];
  __shared__ __align__(16) char Blds[8192];
  __shared__ __align__(16) char T[34816];          // 128 rows x 272B
  const int t = threadIdx.x, lane = t & 63, w = t >> 6;
  const int wr = w >> 1, wc = w & 1;
  const int m0 = blockIdx.x * 128;
  const int by = blockIdx.y;
  const int mode = by >> 3;                        // 0=Q 1=K 2=V
  const bf16* X = mode == 0 ? xq : mode == 1 ? xk : xv;
  const int n0 = by * 128;                         // row into Wqkv (3072 rows)
  f32x4 acc[4][4] = {};
  for (int kt = 0; kt < 32; ++kt) {
    stage_tile<128, 1>(X, m0, kt * 32, 1024, Alds);
    stage_tile<128, 1>(Wqkv, n0, kt * 32, 1024, Blds);
    __syncthreads();
    bf16x8 af[4], bfv[4];
#pragma unroll
    for (int mi = 0; mi < 4; ++mi) af[mi] = ldsfrag(Alds, 128, wr * 64 + mi * 16, 0);
#pragma unroll
    for (int ni = 0; ni < 4; ++ni) bfv[ni] = ldsfrag(Blds, 128, wc * 64 + ni * 16, 0);
#pragma unroll
    for (int mi = 0; mi < 4; ++mi)
#pragma unroll
      for (int ni = 0; ni < 4; ++ni)
        acc[mi][ni] = MFMA16(af[mi], bfv[ni], acc[mi][ni]);
    __syncthreads();
  }
  const int g = lane >> 4, l15 = lane & 15;
  if (mode < 2) {
    const float pscale = (mode == 0) ? SCALE2 : 1.0f;
#pragma unroll
    for (int mi = 0; mi < 4; ++mi)
#pragma unroll
      for (int ni = 0; ni < 4; ++ni)
#pragma unroll
        for (int r = 0; r < 4; ++r) {
          int row = wr * 64 + mi * 16 + g * 4 + r;
          int col = wc * 64 + ni * 16 + l15;
          *(bf16*)(T + row * 272 + col * 2) = (bf16)(acc[mi][ni][r] * pscale);
        }
  } else {
#pragma unroll
    for (int mi = 0; mi < 4; ++mi)
#pragma unroll
      for (int ni = 0; ni < 4; ++ni)
#pragma unroll
        for (int r = 0; r < 4; ++r) {
          int row = wr * 64 + mi * 16 + g * 4 + r;
          int col = wc * 64 + ni * 16 + l15;
          int e = (row & 1) * 64 + (row >> 1);
          *(bf16*)(T + col * 272 + e * 2) = (bf16)acc[mi][ni][r];
        }
  }
  __syncthreads();
  bf16* out = mode == 0 ? Qo : mode == 1 ? Ko : Vt;
  const int nbase = (by & 7) * 128;
  if (mode < 2) {
#pragma unroll
    for (int i = 0; i < 8; ++i) {
      int strip = i * 32 + (t >> 3), j = t & 7;
      int row = strip >> 1, hh = strip & 1;
      bf16x8 v = *(const bf16x8*)(T + row * 272 + hh * 128 + j * 16);
      int mg = m0 + row, s = mg >> 1, b = mg & 1;
      int h = (nbase >> 6) + hh;
      *(bf16x8*)(out + ((size_t)(b * 16 + h) * 2048 + s) * 64 + j * 8) = v;
    }
  } else {
#pragma unroll
    for (int i = 0; i < 8; ++i) {
      int strip = i * 32 + (t >> 3), j = t & 7;
      int col = strip >> 1, b = strip & 1;
      bf16x8 v = *(const bf16x8*)(T + col * 272 + b * 128 + j * 16);
      int n = nbase + col, h = n >> 6, d = n & 63;
      *(bf16x8*)(out + ((size_t)(b * 16 + h) * 64 + d) * 2048 + (m0 >> 1) + j * 8) = v;
    }
  }
}

// ---------------- out-projection GEMM: out = O @ Wo^T + bo, 64x128 tile ----------------
__launch_bounds__(256, 4)
__global__ void k_outproj(const bf16* __restrict__ X, const bf16* __restrict__ W,
                          const float* __restrict__ bias, float* __restrict__ out) {
  __shared__ __align__(16) char Alds[4096];        // 64 x 32 bf16
  __shared__ __align__(16) char Blds[8192];        // 128 x 32 bf16
  const int t = threadIdx.x, lane = t & 63, w = t >> 6;   // 4 waves, each 64x32 cols
  const int g = lane >> 4, l15 = lane & 15;
  const int m0 = blockIdx.x * 64, n0 = blockIdx.y * 128;
  f32x4 acc[4][2] = {};
  for (int kt = 0; kt < 32; ++kt) {
    stage_tile<64, 1>(X, m0, kt * 32, 1024, Alds);
    stage_tile<128, 1>(W, n0, kt * 32, 1024, Blds);
    __syncthreads();
    bf16x8 af[4], bfv[2];
#pragma unroll
    for (int mi = 0; mi < 4; ++mi) af[mi] = ldsfrag(Alds, 64, mi * 16, 0);
#pragma unroll
    for (int ni = 0; ni < 2; ++ni) bfv[ni] = ldsfrag(Blds, 128, w * 32 + ni * 16, 0);
#pragma unroll
    for (int mi = 0; mi < 4; ++mi)
#pragma unroll
      for (int ni = 0; ni < 2; ++ni)
        acc[mi][ni] = MFMA16(af[mi], bfv[ni], acc[mi][ni]);
    __syncthreads();
  }
#pragma unroll
  for (int mi = 0; mi < 4; ++mi)
#pragma unroll
    for (int ni = 0; ni < 2; ++ni)
#pragma unroll
      for (int r = 0; r < 4; ++r) {
        int row = m0 + mi * 16 + g * 4 + r;
        int col = n0 + w * 32 + ni * 16 + l15;
        out[(size_t)row * 1024 + col] = acc[mi][ni][r] + bias[col];
      }
}

// ---------------- attention pass 1: per-row 1/sum(exp2) -------------------------------
// Swapped QK^T, permuted K rows, K double-buffered, 32KB LDS -> 4 blocks/CU.
__launch_bounds__(256, 4)
__global__ void k_sums(const bf16* __restrict__ Qg, const bf16* __restrict__ Kg,
                       const unsigned long long* __restrict__ vm,
                       float* __restrict__ rowsum) {
  __shared__ __align__(16) char Klds[32768];       // 2 x 16KB dbuf
  __shared__ float comb[256];
  const int t = threadIdx.x, lane = t & 63, w = t >> 6;
  const int wr = w >> 1, wc = w & 1;
  const int g = lane >> 4, l15 = lane & 15;
  const int lin = blockIdx.x;
  const int xcd = lin & 7, idx = lin >> 3;
  const int bh = xcd * 4 + (idx >> 4);
  const int q0 = (idx & 15) * 128;
  const int b = bh >> 4;
  const bf16* Qb = Qg + (size_t)bh * 2048 * 64;
  const bf16* Kb = Kg + (size_t)bh * 2048 * 64;

  bf16x8 qreg[4][2];
#pragma unroll
  for (int qi = 0; qi < 4; ++qi)
#pragma unroll
    for (int ks = 0; ks < 2; ++ks) {
      int q = q0 + wr * 64 + qi * 16 + l15;
      qreg[qi][ks] = *(const bf16x8*)(Qb + (size_t)q * 64 + ks * 32 + g * 8);
    }

  auto stage_k = [&](int kt, int buf) {
#pragma unroll
    for (int i = 0; i < 4; ++i) {
      int L = i * 4096 + t * 16;
      int row = L >> 7;
      int lslot = ((L >> 4) & 7) ^ (row & 7);
      const bf16* gp = Kb + (size_t)(kt * 128 + row) * 64 + lslot * 8;
      gload_lds16(gp, Klds + buf * 16384 + i * 4096 + (t & 192) * 16);
    }
  };
  auto kread = [&](int buf, int ki, int ks) -> bf16x8 {
    int row = wc * 64 + (ki >> 1) * 32 + ((l15 >> 2) << 3) + ((ki & 1) << 2) + (l15 & 3);
    int off = row * 128 + (((ks * 4 + g) ^ (row & 7)) << 4);
    return *(const bf16x8*)(Klds + buf * 16384 + off);
  };

  float lrun[4] = {0.f, 0.f, 0.f, 0.f};
  stage_k(0, 0);
  __syncthreads();
  for (int kt = 0; kt < 16; ++kt) {
    const int cur = kt & 1;
    if (kt + 1 < 16) stage_k(kt + 1, cur ^ 1);
    unsigned long long wbq[4];
#pragma unroll
    for (int qi = 0; qi < 4; ++qi) {
      int q = q0 + wr * 64 + qi * 16 + l15;
      wbq[qi] = vm[((size_t)b * 2048 + q) * 32 + kt * 2 + wc];
    }
#pragma unroll
    for (int ki = 0; ki < 4; ++ki) {
      bf16x8 kf0 = kread(cur, ki, 0), kf1 = kread(cur, ki, 1);
#pragma unroll
      for (int qi = 0; qi < 4; ++qi) {
        f32x4 z = {};
        z = MFMA16(kf0, qreg[qi][0], z);
        f32x4 sck = MFMA16(kf1, qreg[qi][1], z);
        uint32_t word = (ki >= 2) ? (uint32_t)(wbq[qi] >> 32) : (uint32_t)wbq[qi];
        int base = g * 8 + (ki & 1) * 4;
        float ps = 0.f;
#pragma unroll
        for (int r = 0; r < 4; ++r) {
          float e = __builtin_exp2f(sck[r]);
          ps += ((word >> (base + r)) & 1u) ? e : 0.f;
        }
        lrun[qi] += ps;
      }
    }
    __syncthreads();
  }
#pragma unroll
  for (int qi = 0; qi < 4; ++qi) {
    float l = lrun[qi];
    l += __shfl_xor(l, 16);
    l += __shfl_xor(l, 32);
    if (g == 0) comb[wc * 128 + wr * 64 + qi * 16 + l15] = l;
  }
  __syncthreads();
  if (t < 128) {
    float L = comb[t] + comb[128 + t];
    rowsum[(size_t)bh * 2048 + q0 + t] = (L > 0.f) ? 1.0f / L : 0.f;
  }
}

// ---------------- attention pass 2: attn write + O = attn @ V --------------------------
__launch_bounds__(256, 2)
__global__ void k_attn2(const bf16* __restrict__ Qg, const bf16* __restrict__ Kg,
                        const bf16* __restrict__ Vtg,
                        const unsigned long long* __restrict__ vm,
                        const float* __restrict__ rowsum,
                        float* __restrict__ attn, bf16* __restrict__ Obf) {
  __shared__ __align__(16) char LDS[65536];
  char* Klds = LDS;             // 2 x 16KB: [128 k][64 d] bf16, swizzled
  char* Vlds = LDS + 32768;     // 2 x 16KB: [64 d][128 k] bf16, swizzled
  const int t = threadIdx.x, lane = t & 63, w = t >> 6;
  const int wr = w >> 1, wc = w & 1;
  const int g = lane >> 4, l15 = lane & 15;
  const int lin = blockIdx.x;
  const int xcd = lin & 7, idx = lin >> 3;
  const int bh = xcd * 4 + (idx >> 4);
  const int q0 = (idx & 15) * 128;
  const int b = bh >> 4, h = bh & 15;
  const bf16* Qb = Qg  + (size_t)bh * 2048 * 64;
  const bf16* Kb = Kg  + (size_t)bh * 2048 * 64;
  const bf16* Vb = Vtg + (size_t)bh * 64 * 2048;

  bf16x8 qreg[4][2];
  float R[4];
#pragma unroll
  for (int qi = 0; qi < 4; ++qi) {
    int q = q0 + wr * 64 + qi * 16 + l15;
    R[qi] = rowsum[(size_t)bh * 2048 + q];
#pragma unroll
    for (int ks = 0; ks < 2; ++ks)
      qreg[qi][ks] = *(const bf16x8*)(Qb + (size_t)q * 64 + ks * 32 + g * 8);
  }

  auto stage_k = [&](int kt, int buf) {
#pragma unroll
    for (int i = 0; i < 4; ++i) {
      int L = i * 4096 + t * 16;
      int row = L >> 7;
      int lslot = ((L >> 4) & 7) ^ (row & 7);
      const bf16* gp = Kb + (size_t)(kt * 128 + row) * 64 + lslot * 8;
      gload_lds16(gp, Klds + buf * 16384 + i * 4096 + (t & 192) * 16);
    }
  };
  auto stage_v = [&](int kt, int buf) {
#pragma unroll
    for (int i = 0; i < 4; ++i) {
      int L = i * 4096 + t * 16;
      int row = L >> 8;
      int lslot = ((L >> 4) & 15) ^ (row & 7);
      const bf16* gp = Vb + (size_t)row * 2048 + kt * 128 + lslot * 8;
      gload_lds16(gp, Vlds + buf * 16384 + i * 4096 + (t & 192) * 16);
    }
  };
  auto kread = [&](int buf, int ki, int ks) -> bf16x8 {
    int row = wc * 64 + (ki >> 1) * 32 + ((l15 >> 2) << 3) + ((ki & 1) << 2) + (l15 & 3);
    int off = row * 128 + (((ks * 4 + g) ^ (row & 7)) << 4);
    return *(const bf16x8*)(Klds + buf * 16384 + off);
  };
  auto vread = [&](int buf, int di, int kp) -> bf16x8 {
    int row = di * 16 + l15;
    int off = row * 256 + wc * 128 + (((kp * 4 + g) ^ (l15 & 7)) << 4);
    return *(const bf16x8*)(Vlds + buf * 16384 + off);
  };

  f32x4 oacc[4][4] = {};                    // [di][qi]
  stage_k(0, 0);
  stage_v(0, 0);
  __syncthreads();
  for (int kt = 0; kt < 16; ++kt) {
    const int cur = kt & 1;
    if (kt + 1 < 16) { stage_k(kt + 1, cur ^ 1); stage_v(kt + 1, cur ^ 1); }
    unsigned long long wbq[4];
#pragma unroll
    for (int qi = 0; qi < 4; ++qi) {
      int q = q0 + wr * 64 + qi * 16 + l15;
      wbq[qi] = vm[((size_t)b * 2048 + q) * 32 + kt * 2 + wc];
    }
    bf16x8 pf[4][2];                        // [qi][kp] in-register P fragments
#pragma unroll
    for (int ki = 0; ki < 4; ++ki) {
      bf16x8 kf0 = kread(cur, ki, 0), kf1 = kread(cur, ki, 1);
#pragma unroll
      for (int qi = 0; qi < 4; ++qi) {
        f32x4 z = {};
        z = MFMA16(kf0, qreg[qi][0], z);
        f32x4 sck = MFMA16(kf1, qreg[qi][1], z);
        int q = q0 + wr * 64 + qi * 16 + l15;
        int colbase = (ki >> 1) * 32 + g * 8 + (ki & 1) * 4;
        uint32_t word = (ki >= 2) ? (uint32_t)(wbq[qi] >> 32) : (uint32_t)wbq[qi];
        int base = g * 8 + (ki & 1) * 4;
        f32x4 pv;
#pragma unroll
        for (int r = 0; r < 4; ++r) {
          float selR = ((word >> (base + r)) & 1u) ? R[qi] : 0.f;
          float p = __builtin_exp2f(sck[r]) * selR;
          pv[r] = p;
          pf[qi][ki >> 1][(ki & 1) * 4 + r] = (bf16)p;
        }
        *(f32x4*)(attn + ((size_t)bh * 2048 + q) * 2048 + kt * 128 + wc * 64 + colbase) = pv;
      }
    }
    // PV: oacc[di][qi] += V^T(d,k) * P(q,k) over this kt's 64 k (wc half)
#pragma unroll
    for (int kp = 0; kp < 2; ++kp) {
      bf16x8 vf[4];
#pragma unroll
      for (int di = 0; di < 4; ++di) vf[di] = vread(cur, di, kp);
#pragma unroll
      for (int di = 0; di < 4; ++di)
#pragma unroll
        for (int qi = 0; qi < 4; ++qi)
          oacc[di][qi] = MFMA16(vf[di], pf[qi][kp], oacc[di][qi]);
    }
    __syncthreads();
  }

  // ---- combine wc=0 + wc=1 partial O and store ----
  char* Ob = LDS + 32768 + wr * 16384;      // [64 q][64 d] f32, swizzled
  if (wc == 0) {
#pragma unroll
    for (int di = 0; di < 4; ++di)
#pragma unroll
      for (int qi = 0; qi < 4; ++qi) {
        int ql = qi * 16 + l15;
        int off = ql * 256 + ((di * 64 + g * 16) ^ ((ql & 7) << 4));
        *(f32x4*)(Ob + off) = oacc[di][qi];
      }
  }
  __syncthreads();
  if (wc == 1) {
#pragma unroll
    for (int di = 0; di < 4; ++di)
#pragma unroll
      for (int qi = 0; qi < 4; ++qi) {
        int ql = qi * 16 + l15;
        int off = ql * 256 + ((di * 64 + g * 16) ^ ((ql & 7) << 4));
        f32x4 o2 = *(const f32x4*)(Ob + off);
        f32x4 o = oacc[di][qi] + o2;
        bf16x4 ob;
#pragma unroll
        for (int r = 0; r < 4; ++r) ob[r] = (bf16)o[r];
        int q = q0 + wr * 64 + ql;
        size_t m = (size_t)q * 2 + b;
        *(bf16x4*)(Obf + m * 1024 + h * 64 + di * 16 + g * 4) = ob;
      }
  }
}

extern "C" void kernel_launch(void* const* d_in, const int* in_sizes, int n_in,
                              void* d_out, int out_size, void* d_ws, size_t ws_size,
                              hipStream_t stream) {
  (void)in_sizes; (void)n_in; (void)out_size; (void)ws_size;
  const float* qin = (const float*)d_in[0];
  const float* kin = (const float*)d_in[1];
  const float* vin = (const float*)d_in[2];
  const int*  mask = (const int*)d_in[3];
  const int*  kpm  = (const int*)d_in[4];
  const float* wq  = (const float*)d_in[5];
  const float* wk  = (const float*)d_in[6];
  const float* wv  = (const float*)d_in[7];
  const float* wo  = (const float*)d_in[8];
  const float* bo  = (const float*)d_in[9];
  float* out  = (float*)d_out;           // (S,B,D) = 4194304 floats
  float* attn = out + 4194304;           // (B,H,S,S) = 134217728 floats

  char* ws = (char*)d_ws;
  size_t off = 0;
  auto alloc = [&](size_t bytes) { char* p = ws + off; off += (bytes + 255) & ~(size_t)255; return p; };
  bf16* wqkv = (bf16*)alloc(6291456);    // [3072][1024]
  bf16* wob  = (bf16*)alloc(2097152);
  bf16* xq  = (bf16*)alloc(8388608);
  bf16* xk  = (bf16*)alloc(8388608);
  bf16* xv  = (bf16*)alloc(8388608);
  bf16* Qb  = (bf16*)alloc(8388608);
  bf16* Kb  = (bf16*)alloc(8388608);
  bf16* Vt  = (bf16*)alloc(8388608);
  bf16* Obf = (bf16*)alloc(8388608);
  unsigned long long* vmask = (unsigned long long*)alloc((size_t)131072 * 8);
  float* rowsum = (float*)alloc((size_t)32 * 2048 * 4);

  k_cvt<<<8192, 256, 0, stream>>>(qin, kin, vin, wq, wk, wv, wo,
                                  xq, xk, xv, wqkv, wob);
  k_maskpack<<<512, 256, 0, stream>>>(mask, kpm, vmask);
  k_proj<<<dim3(32, 24), 256, 0, stream>>>(xq, xk, xv, wqkv, Qb, Kb, Vt);
  k_sums<<<512, 256, 0, stream>>>(Qb, Kb, vmask, rowsum);
  k_attn2<<<512, 256, 0, stream>>>(Qb, Kb, Vt, vmask, rowsum, attn, Obf);
  k_outproj<<<dim3(64, 8), 256, 0, stream>>>(Obf, wob, bo, out);
}

// Round 6
// 303.437 us; speedup vs baseline: 1.1791x; 1.1791x over previous
//
#include <hip/hip_runtime.h>
#include <cstdint>

typedef __bf16 bf16;
typedef __bf16 bf16x8 __attribute__((ext_vector_type(8)));
typedef __bf16 bf16x4 __attribute__((ext_vector_type(4)));
typedef float  f32x4  __attribute__((ext_vector_type(4)));

#define MFMA16(a,b,c) __builtin_amdgcn_mfma_f32_16x16x32_bf16((a),(b),(c),0,0,0)
#define SCALE2 0.18033688011f   /* 0.125 * log2(e), folded into Q projection */

__device__ __forceinline__ void gload_lds16(const void* g, void* lds) {
  __builtin_amdgcn_global_load_lds((const __attribute__((address_space(1))) uint32_t*)g,
                                   (__attribute__((address_space(3))) uint32_t*)lds, 16, 0, 0);
}

// Stage a [rows=R] x [BK=PANELS*32] bf16 tile from global (row-major, leading dim ld)
// into LDS as PANELS x [R][32] panels, linear order, via global_load_lds width=16.
template<int R, int PANELS>
__device__ __forceinline__ void stage_tile(const bf16* __restrict__ g, int r0, int k0,
                                           int ld, char* lds) {
  const int t = threadIdx.x;
  constexpr int NISSUE = (PANELS * R * 64) / 4096;   // bytes/4096 (256 thr * 16B)
#pragma unroll
  for (int i = 0; i < NISSUE; ++i) {
    int idx = i * 256 + t;
    int c = idx & 3;                 // 16B chunk within 32-elem panel row
    int r = (idx >> 2) & (R - 1);    // row
    int p = idx / (4 * R);           // panel
    const bf16* gp = g + (size_t)(r0 + r) * ld + (k0 + p * 32 + c * 8);
    char* lp = lds + i * 4096 + (t & 192) * 16;      // wave-uniform base; HW adds lane*16
    gload_lds16(gp, lp);
  }
}

// Read an MFMA fragment (8 bf16, k-contiguous) from a panel-32 LDS tile.
__device__ __forceinline__ bf16x8 ldsfrag(const char* lds, int R, int rowBase, int panel) {
  const int lane = threadIdx.x & 63;
  int off = ((panel * R + rowBase + (lane & 15)) * 32 + (lane >> 4) * 8) * 2;
  return *(const bf16x8*)(lds + off);
}

// ---------------- convert fp32 -> bf16 (inputs + weights) ----------------
__global__ void k_cvt(const float* __restrict__ qin, const float* __restrict__ kin,
                      const float* __restrict__ vin,
                      const float* __restrict__ wq, const float* __restrict__ wk,
                      const float* __restrict__ wv, const float* __restrict__ wo,
                      bf16* __restrict__ oq, bf16* __restrict__ ok, bf16* __restrict__ ov,
                      bf16* __restrict__ wqkv, bf16* __restrict__ owo) {
  long i = (long)blockIdx.x * 256 + threadIdx.x;   // chunk of 8 elems; 2097152 total
  const float* s; bf16* d; long off;
  if (i < 524288)       { s = qin; d = oq; off = i; }
  else if (i < 1048576) { s = kin; d = ok; off = i - 524288; }
  else if (i < 1572864) { s = vin; d = ov; off = i - 1048576; }
  else {
    long j = i - 1572864; int sel = (int)(j >> 17); off = j & 131071;
    s = sel == 0 ? wq : sel == 1 ? wk : sel == 2 ? wv : wo;
    d = sel == 3 ? owo : wqkv + (size_t)sel * 1048576;
  }
  const float4* sp = (const float4*)s + off * 2;
  float4 a = sp[0], b = sp[1];
  bf16x8 o;
  o[0] = (bf16)a.x; o[1] = (bf16)a.y; o[2] = (bf16)a.z; o[3] = (bf16)a.w;
  o[4] = (bf16)b.x; o[5] = (bf16)b.y; o[6] = (bf16)b.z; o[7] = (bf16)b.w;
  *((bf16x8*)d + off) = o;
}

// ---------------- pack mask & key_padding_mask into bit-words ----------------
__global__ void k_maskpack(const int* __restrict__ mask, const int* __restrict__ kpm,
                           unsigned long long* __restrict__ vm) {
  int i = blockIdx.x * 256 + threadIdx.x;          // [b][q][w] word; 131072 total
  int w = i & 31, q = (i >> 5) & 2047, b = i >> 16;
  const int4* mrow = (const int4*)(mask + (size_t)q * 2048 + w * 64);
  const int4* krow = (const int4*)(kpm + (size_t)b * 2048 + w * 64);
  unsigned long long bits = 0;
#pragma unroll
  for (int j = 0; j < 16; ++j) {
    int4 m4 = mrow[j], k4 = krow[j];
    bits |= (unsigned long long)((m4.x != 0) & (k4.x != 0)) << (j * 4 + 0);
    bits |= (unsigned long long)((m4.y != 0) & (k4.y != 0)) << (j * 4 + 1);
    bits |= (unsigned long long)((m4.z != 0) & (k4.z != 0)) << (j * 4 + 2);
    bits |= (unsigned long long)((m4.w != 0) & (k4.w != 0)) << (j * 4 + 3);
  }
  vm[i] = bits;
}

// ---------------- combined QKV projection: C = X @ Wqkv[n0:n0+128]^T ----------------
// BK=64 double-buffered staging; transpose buffer T aliases the staging LDS.
// mode 0 (Q) epilogue pre-folds SCALE2 so the attention exp chain needs no multiply.
__launch_bounds__(256, 2)
__global__ void k_proj(const bf16* __restrict__ xq, const bf16* __restrict__ xk,
                       const bf16* __restrict__ xv, const bf16* __restrict__ Wqkv,
                       bf16* __restrict__ Qo, bf16* __restrict__ Ko,
                       bf16* __restrict__ Vt) {
  __shared__ __align__(16) char LDS[65536];        // 2 bufs x (A 16KB + B 16KB); T aliases
  const int t = threadIdx.x, lane = t & 63, w = t >> 6;
  const int wr = w >> 1, wc = w & 1;
  const int m0 = blockIdx.x * 128;
  const int by = blockIdx.y;
  const int mode = by >> 3;                        // 0=Q 1=K 2=V
  const bf16* X = mode == 0 ? xq : mode == 1 ? xk : xv;
  const int n0 = by * 128;                         // row into Wqkv (3072 rows)
  f32x4 acc[4][4] = {};
  stage_tile<128, 2>(X, m0, 0, 1024, LDS);
  stage_tile<128, 2>(Wqkv, n0, 0, 1024, LDS + 16384);
  __syncthreads();
  for (int kt = 0; kt < 16; ++kt) {
    char* Ab = LDS + (kt & 1) * 32768;
    char* Bb = Ab + 16384;
    if (kt + 1 < 16) {
      char* An = LDS + ((kt + 1) & 1) * 32768;
      stage_tile<128, 2>(X, m0, (kt + 1) * 64, 1024, An);
      stage_tile<128, 2>(Wqkv, n0, (kt + 1) * 64, 1024, An + 16384);
    }
#pragma unroll
    for (int ks = 0; ks < 2; ++ks) {
      bf16x8 af[4], bfv[4];
#pragma unroll
      for (int mi = 0; mi < 4; ++mi) af[mi] = ldsfrag(Ab, 128, wr * 64 + mi * 16, ks);
#pragma unroll
      for (int ni = 0; ni < 4; ++ni) bfv[ni] = ldsfrag(Bb, 128, wc * 64 + ni * 16, ks);
#pragma unroll
      for (int mi = 0; mi < 4; ++mi)
#pragma unroll
        for (int ni = 0; ni < 4; ++ni)
          acc[mi][ni] = MFMA16(af[mi], bfv[ni], acc[mi][ni]);
    }
    __syncthreads();
  }
  char* T = LDS;                                   // 128 rows x 272B, aliases staging
  const int g = lane >> 4, l15 = lane & 15;
  if (mode < 2) {
    const float pscale = (mode == 0) ? SCALE2 : 1.0f;
#pragma unroll
    for (int mi = 0; mi < 4; ++mi)
#pragma unroll
      for (int ni = 0; ni < 4; ++ni)
#pragma unroll
        for (int r = 0; r < 4; ++r) {
          int row = wr * 64 + mi * 16 + g * 4 + r;
          int col = wc * 64 + ni * 16 + l15;
          *(bf16*)(T + row * 272 + col * 2) = (bf16)(acc[mi][ni][r] * pscale);
        }
  } else {
#pragma unroll
    for (int mi = 0; mi < 4; ++mi)
#pragma unroll
      for (int ni = 0; ni < 4; ++ni)
#pragma unroll
        for (int r = 0; r < 4; ++r) {
          int row = wr * 64 + mi * 16 + g * 4 + r;
          int col = wc * 64 + ni * 16 + l15;
          int e = (row & 1) * 64 + (row >> 1);
          *(bf16*)(T + col * 272 + e * 2) = (bf16)acc[mi][ni][r];
        }
  }
  __syncthreads();
  bf16* out = mode == 0 ? Qo : mode == 1 ? Ko : Vt;
  const int nbase = (by & 7) * 128;
  if (mode < 2) {
#pragma unroll
    for (int i = 0; i < 8; ++i) {
      int strip = i * 32 + (t >> 3), j = t & 7;
      int row = strip >> 1, hh = strip & 1;
      bf16x8 v = *(const bf16x8*)(T + row * 272 + hh * 128 + j * 16);
      int mg = m0 + row, s = mg >> 1, b = mg & 1;
      int h = (nbase >> 6) + hh;
      *(bf16x8*)(out + ((size_t)(b * 16 + h) * 2048 + s) * 64 + j * 8) = v;
    }
  } else {
#pragma unroll
    for (int i = 0; i < 8; ++i) {
      int strip = i * 32 + (t >> 3), j = t & 7;
      int col = strip >> 1, b = strip & 1;
      bf16x8 v = *(const bf16x8*)(T + col * 272 + b * 128 + j * 16);
      int n = nbase + col, h = n >> 6, d = n & 63;
      *(bf16x8*)(out + ((size_t)(b * 16 + h) * 64 + d) * 2048 + (m0 >> 1) + j * 8) = v;
    }
  }
}

// ---------------- out-projection GEMM: out = O @ Wo^T + bo, BK=64 dbuf ----------------
__launch_bounds__(256, 2)
__global__ void k_outproj(const bf16* __restrict__ X, const bf16* __restrict__ W,
                          const float* __restrict__ bias, float* __restrict__ out) {
  __shared__ __align__(16) char LDS[65536];
  const int t = threadIdx.x, lane = t & 63, w = t >> 6;
  const int wr = w >> 1, wc = w & 1;
  const int m0 = blockIdx.x * 128, n0 = blockIdx.y * 128;
  f32x4 acc[4][4] = {};
  stage_tile<128, 2>(X, m0, 0, 1024, LDS);
  stage_tile<128, 2>(W, n0, 0, 1024, LDS + 16384);
  __syncthreads();
  for (int kt = 0; kt < 16; ++kt) {
    char* Ab = LDS + (kt & 1) * 32768;
    char* Bb = Ab + 16384;
    if (kt + 1 < 16) {
      char* An = LDS + ((kt + 1) & 1) * 32768;
      stage_tile<128, 2>(X, m0, (kt + 1) * 64, 1024, An);
      stage_tile<128, 2>(W, n0, (kt + 1) * 64, 1024, An + 16384);
    }
#pragma unroll
    for (int ks = 0; ks < 2; ++ks) {
      bf16x8 af[4], bfv[4];
#pragma unroll
      for (int mi = 0; mi < 4; ++mi) af[mi] = ldsfrag(Ab, 128, wr * 64 + mi * 16, ks);
#pragma unroll
      for (int ni = 0; ni < 4; ++ni) bfv[ni] = ldsfrag(Bb, 128, wc * 64 + ni * 16, ks);
#pragma unroll
      for (int mi = 0; mi < 4; ++mi)
#pragma unroll
        for (int ni = 0; ni < 4; ++ni)
          acc[mi][ni] = MFMA16(af[mi], bfv[ni], acc[mi][ni]);
    }
    __syncthreads();
  }
  const int g = lane >> 4, l15 = lane & 15;
#pragma unroll
  for (int mi = 0; mi < 4; ++mi)
#pragma unroll
    for (int ni = 0; ni < 4; ++ni)
#pragma unroll
      for (int r = 0; r < 4; ++r) {
        int row = m0 + wr * 64 + mi * 16 + g * 4 + r;
        int col = n0 + wc * 64 + ni * 16 + l15;
        out[(size_t)row * 1024 + col] = acc[mi][ni][r] + bias[col];
      }
}

// ---------------- fused attention (permuted-K, in-register P, dbuf, XCD swizzle) ----
// Swapped QK^T: sc = mfma(Kfrag, Qfrag) -> C[row=k][col=q]. K rows are loaded in a
// permuted order so each lane's output quads (ki even|odd) concatenate in-register
// into the exact x32 B-fragment for PV. Q pre-scaled by 0.125*log2e in projection;
// mask applied as select-after-exp2 (exp2 arg bounded ~|12|, no overflow).
__launch_bounds__(256, 2)
__global__ void k_attn(const bf16* __restrict__ Qg, const bf16* __restrict__ Kg,
                       const bf16* __restrict__ Vtg,
                       const unsigned long long* __restrict__ vm,
                       float* __restrict__ attn, bf16* __restrict__ Obf) {
  __shared__ __align__(16) char LDS[65536];
  char* Klds = LDS;             // 2 x 16KB: [128 k][64 d] bf16, swizzled
  char* Vlds = LDS + 32768;     // 2 x 16KB: [64 d][128 k] bf16, swizzled
  const int t = threadIdx.x, lane = t & 63, w = t >> 6;
  const int wr = w >> 1, wc = w & 1;          // wr: q-half, wc: k-half
  const int g = lane >> 4, l15 = lane & 15;

  // XCD swizzle: lin%8 = XCD; each XCD owns 4 heads x 16 q-blocks (all co-resident)
  const int lin = blockIdx.x + 16 * blockIdx.y;
  const int xcd = lin & 7, idx = lin >> 3;
  const int bh = xcd * 4 + (idx >> 4);
  const int q0 = (idx & 15) * 128;
  const int b = bh >> 4, h = bh & 15;

  const bf16* Qb = Qg  + (size_t)bh * 2048 * 64;
  const bf16* Kb = Kg  + (size_t)bh * 2048 * 64;
  const bf16* Vb = Vtg + (size_t)bh * 64 * 2048;

  // Q fragments held in registers for the whole kernel
  bf16x8 qreg[4][2];
#pragma unroll
  for (int qi = 0; qi < 4; ++qi)
#pragma unroll
    for (int ks = 0; ks < 2; ++ks) {
      int q = q0 + wr * 64 + qi * 16 + l15;
      qreg[qi][ks] = *(const bf16x8*)(Qb + (size_t)q * 64 + ks * 32 + g * 8);
    }

  auto stage_k = [&](int kt, int buf) {
#pragma unroll
    for (int i = 0; i < 4; ++i) {
      int L = i * 4096 + t * 16;
      int row = L >> 7;
      int lslot = ((L >> 4) & 7) ^ (row & 7);
      const bf16* gp = Kb + (size_t)(kt * 128 + row) * 64 + lslot * 8;
      gload_lds16(gp, Klds + buf * 16384 + i * 4096 + (t & 192) * 16);
    }
  };
  auto stage_v = [&](int kt, int buf) {
#pragma unroll
    for (int i = 0; i < 4; ++i) {
      int L = i * 4096 + t * 16;
      int row = L >> 8;
      int lslot = ((L >> 4) & 15) ^ (row & 7);
      const bf16* gp = Vb + (size_t)row * 2048 + kt * 128 + lslot * 8;
      gload_lds16(gp, Vlds + buf * 16384 + i * 4096 + (t & 192) * 16);
    }
  };
  // permuted K-row read: A-row i=l15 holds K row (wc-half) (ki>>1)*32+(i>>2)*8+(ki&1)*4+(i&3)
  auto kread = [&](int buf, int ki, int ks) -> bf16x8 {
    int row = wc * 64 + (ki >> 1) * 32 + ((l15 >> 2) << 3) + ((ki & 1) << 2) + (l15 & 3);
    int off = row * 128 + (((ks * 4 + g) ^ (row & 7)) << 4);
    return *(const bf16x8*)(Klds + buf * 16384 + off);
  };
  auto vread = [&](int buf, int di, int kp) -> bf16x8 {
    int row = di * 16 + l15;
    int off = row * 256 + wc * 128 + (((kp * 4 + g) ^ (l15 & 7)) << 4);
    return *(const bf16x8*)(Vlds + buf * 16384 + off);
  };

  // ---- phase 1: per-row sum of exp2 scores, K double-buffered ----
  float lrun[4] = {0.f, 0.f, 0.f, 0.f};
  stage_k(0, 0);
  __syncthreads();
  for (int kt = 0; kt < 16; ++kt) {
    const int cur = kt & 1;
    if (kt + 1 < 16) stage_k(kt + 1, cur ^ 1);
    unsigned long long wbq[4];
#pragma unroll
    for (int qi = 0; qi < 4; ++qi) {
      int q = q0 + wr * 64 + qi * 16 + l15;
      wbq[qi] = vm[((size_t)b * 2048 + q) * 32 + kt * 2 + wc];
    }
    f32x4 sc[4][4] = {};   // [ki][qi]
#pragma unroll
    for (int ks = 0; ks < 2; ++ks) {
      bf16x8 kf[4];
#pragma unroll
      for (int ki = 0; ki < 4; ++ki) kf[ki] = kread(cur, ki, ks);
#pragma unroll
      for (int ki = 0; ki < 4; ++ki)
#pragma unroll
        for (int qi = 0; qi < 4; ++qi)
          sc[ki][qi] = MFMA16(kf[ki], qreg[qi][ks], sc[ki][qi]);
    }
#pragma unroll
    for (int qi = 0; qi < 4; ++qi) {
      uint32_t wlo = (uint32_t)wbq[qi], whi = (uint32_t)(wbq[qi] >> 32);
      float ps = 0.f;
#pragma unroll
      for (int ki = 0; ki < 4; ++ki) {
        uint32_t word = (ki >= 2) ? whi : wlo;
        int base = g * 8 + (ki & 1) * 4;
#pragma unroll
        for (int r = 0; r < 4; ++r) {
          float e = __builtin_exp2f(sc[ki][qi][r]);
          ps += ((word >> (base + r)) & 1u) ? e : 0.f;
        }
      }
      lrun[qi] += ps;
    }
    __syncthreads();
  }

  // ---- reduce across lanes, then merge the two k-halves per q-row ----
  float* comb = (float*)Vlds;              // V region unused in phase 1
#pragma unroll
  for (int qi = 0; qi < 4; ++qi) {
    float l = lrun[qi];
    l += __shfl_xor(l, 16);
    l += __shfl_xor(l, 32);
    if (g == 0) comb[wc * 128 + wr * 64 + qi * 16 + l15] = l;
  }
  __syncthreads();
  float R[4];
#pragma unroll
  for (int qi = 0; qi < 4; ++qi) {
    float L = comb[wr * 64 + qi * 16 + l15] + comb[128 + wr * 64 + qi * 16 + l15];
    R[qi] = (L > 0.f) ? 1.0f / L : 0.f;
  }
  __syncthreads();

  // ---- phase 2: attn write + O = attn @ V, K+V double-buffered, P in registers ----
  f32x4 oacc[4][4] = {};                    // [di][qi]
  stage_k(0, 0);
  stage_v(0, 0);
  __syncthreads();
  for (int kt = 0; kt < 16; ++kt) {
    const int cur = kt & 1;
    if (kt + 1 < 16) { stage_k(kt + 1, cur ^ 1); stage_v(kt + 1, cur ^ 1); }
    unsigned long long wbq[4];
#pragma unroll
    for (int qi = 0; qi < 4; ++qi) {
      int q = q0 + wr * 64 + qi * 16 + l15;
      wbq[qi] = vm[((size_t)b * 2048 + q) * 32 + kt * 2 + wc];
    }
    bf16x8 pf[4][2];                        // [qi][kp] in-register P fragments
#pragma unroll
    for (int ki = 0; ki < 4; ++ki) {
      bf16x8 kf0 = kread(cur, ki, 0), kf1 = kread(cur, ki, 1);
#pragma unroll
      for (int qi = 0; qi < 4; ++qi) {
        f32x4 z = {};
        z = MFMA16(kf0, qreg[qi][0], z);
        f32x4 sck = MFMA16(kf1, qreg[qi][1], z);
        int q = q0 + wr * 64 + qi * 16 + l15;
        int colbase = (ki >> 1) * 32 + g * 8 + (ki & 1) * 4;
        uint32_t word = (ki >= 2) ? (uint32_t)(wbq[qi] >> 32) : (uint32_t)wbq[qi];
        int base = g * 8 + (ki & 1) * 4;
        f32x4 pv;
#pragma unroll
        for (int r = 0; r < 4; ++r) {
          float selR = ((word >> (base + r)) & 1u) ? R[qi] : 0.f;
          float p = __builtin_exp2f(sck[r]) * selR;
          pv[r] = p;
          pf[qi][ki >> 1][(ki & 1) * 4 + r] = (bf16)p;
        }
        *(f32x4*)(attn + ((size_t)bh * 2048 + q) * 2048 + kt * 128 + wc * 64 + colbase) = pv;
      }
    }
    // PV: oacc[di][qi] += V^T(d,k) * P(q,k) over this kt's 64 k (wc half)
#pragma unroll
    for (int kp = 0; kp < 2; ++kp) {
      bf16x8 vf[4];
#pragma unroll
      for (int di = 0; di < 4; ++di) vf[di] = vread(cur, di, kp);
#pragma unroll
      for (int di = 0; di < 4; ++di)
#pragma unroll
        for (int qi = 0; qi < 4; ++qi)
          oacc[di][qi] = MFMA16(vf[di], pf[qi][kp], oacc[di][qi]);
    }
    __syncthreads();
  }

  // ---- combine wc=0 + wc=1 partial O and store ----
  char* Ob = LDS + 32768 + wr * 16384;      // [64 q][64 d] f32, swizzled
  if (wc == 0) {
#pragma unroll
    for (int di = 0; di < 4; ++di)
#pragma unroll
      for (int qi = 0; qi < 4; ++qi) {
        int ql = qi * 16 + l15;
        int off = ql * 256 + ((di * 64 + g * 16) ^ ((ql & 7) << 4));
        *(f32x4*)(Ob + off) = oacc[di][qi];
      }
  }
  __syncthreads();
  if (wc == 1) {
#pragma unroll
    for (int di = 0; di < 4; ++di)
#pragma unroll
      for (int qi = 0; qi < 4; ++qi) {
        int ql = qi * 16 + l15;
        int off = ql * 256 + ((di * 64 + g * 16) ^ ((ql & 7) << 4));
        f32x4 o2 = *(const f32x4*)(Ob + off);
        f32x4 o = oacc[di][qi] + o2;
        bf16x4 ob;
#pragma unroll
        for (int r = 0; r < 4; ++r) ob[r] = (bf16)o[r];
        int q = q0 + wr * 64 + ql;
        size_t m = (size_t)q * 2 + b;
        *(bf16x4*)(Obf + m * 1024 + h * 64 + di * 16 + g * 4) = ob;
      }
  }
}

extern "C" void kernel_launch(void* const* d_in, const int* in_sizes, int n_in,
                              void* d_out, int out_size, void* d_ws, size_t ws_size,
                              hipStream_t stream) {
  (void)in_sizes; (void)n_in; (void)out_size; (void)ws_size;
  const float* qin = (const float*)d_in[0];
  const float* kin = (const float*)d_in[1];
  const float* vin = (const float*)d_in[2];
  const int*  mask = (const int*)d_in[3];
  const int*  kpm  = (const int*)d_in[4];
  const float* wq  = (const float*)d_in[5];
  const float* wk  = (const float*)d_in[6];
  const float* wv  = (const float*)d_in[7];
  const float* wo  = (const float*)d_in[8];
  const float* bo  = (const float*)d_in[9];
  float* out  = (float*)d_out;           // (S,B,D) = 4194304 floats
  float* attn = out + 4194304;           // (B,H,S,S) = 134217728 floats

  char* ws = (char*)d_ws;
  size_t off = 0;
  auto alloc = [&](size_t bytes) { char* p = ws + off; off += (bytes + 255) & ~(size_t)255; return p; };
  bf16* wqkv = (bf16*)alloc(6291456);    // [3072][1024]
  bf16* wob  = (bf16*)alloc(2097152);
  bf16* xq  = (bf16*)alloc(8388608);
  bf16* xk  = (bf16*)alloc(8388608);
  bf16* xv  = (bf16*)alloc(8388608);
  bf16* Qb  = (bf16*)alloc(8388608);
  bf16* Kb  = (bf16*)alloc(8388608);
  bf16* Vt  = (bf16*)alloc(8388608);
  bf16* Obf = (bf16*)alloc(8388608);
  unsigned long long* vmask = (unsigned long long*)alloc((size_t)131072 * 8);

  k_cvt<<<8192, 256, 0, stream>>>(qin, kin, vin, wq, wk, wv, wo,
                                  xq, xk, xv, wqkv, wob);
  k_maskpack<<<512, 256, 0, stream>>>(mask, kpm, vmask);
  k_proj<<<dim3(32, 24), 256, 0, stream>>>(xq, xk, xv, wqkv, Qb, Kb, Vt);
  k_attn<<<dim3(16, 32), 256, 0, stream>>>(Qb, Kb, Vt, vmask, attn, Obf);
  k_outproj<<<dim3(32, 8), 256, 0, stream>>>(Obf, wob, bo, out);
}